// Round 5
// baseline (136.482 us; speedup 1.0000x reference)
//
#include <hip/hip_runtime.h>
#include <math.h>

#define D_MODEL 1024
#define HEAD 64
#define SEQ 2048
#define BATCH 4

typedef _Float16 f16x4 __attribute__((ext_vector_type(4)));
typedef _Float16 f16x8 __attribute__((ext_vector_type(8)));
typedef float f32x4 __attribute__((ext_vector_type(4)));

// ---------------- prepass: wT[192][1024] fp16 from wq/wk/wv fp32 [1024][64] ---
__global__ __launch_bounds__(256) void prep_w(
    const float* __restrict__ wq, const float* __restrict__ wk,
    const float* __restrict__ wv, _Float16* __restrict__ wT)
{
    const float* w = (blockIdx.y == 0) ? wq : (blockIdx.y == 1) ? wk : wv;
    const int kbase = blockIdx.x * 64;
    __shared__ float t[64][65];
    const int tid = threadIdx.x;
    #pragma unroll
    for (int i = 0; i < 16; i++) {
        int idx = tid + i * 256;
        int kk = idx >> 6, c = idx & 63;
        t[kk][c] = w[(size_t)(kbase + kk) * 64 + c];
    }
    __syncthreads();
    #pragma unroll
    for (int i = 0; i < 16; i++) {
        int idx = tid + i * 256;
        int c = idx >> 6, kk = idx & 63;
        wT[(size_t)(blockIdx.y * 64 + c) * 1024 + kbase + kk] = (_Float16)t[kk][c];
    }
}

// ---------------- fused QKV projection, fp16 MFMA, deep reg pipeline ----------
// grid 256 x 512 thr: 32 rows/block. Wave (mt=w>>2, cg=w&3): rows mt*16..+16,
// fused cols [48cg,48cg+48). x prefetched 8 windows (256 k) ahead, wT 4 windows
// ahead, K-loop fully unrolled -> ~20 loads in flight per wave.
__global__ __launch_bounds__(512) void proj_kernel(
    const float* __restrict__ x, const _Float16* __restrict__ wT,
    const float* __restrict__ bq, const float* __restrict__ bk2,
    const float* __restrict__ bv,
    _Float16* __restrict__ q, _Float16* __restrict__ k, _Float16* __restrict__ vT)
{
    const int tid = threadIdx.x;
    const int wave = tid >> 6;
    const int lane = tid & 63;
    const int l16 = lane & 15;
    const int quad = lane >> 4;
    const int row0 = blockIdx.x * 32 + (wave >> 2) * 16;
    const int ncol0 = (wave & 3) * 48;

    const float* xp = x + (size_t)(row0 + l16) * D_MODEL + quad * 8;
    const _Float16* wp0 = wT + (size_t)(ncol0 + l16) * D_MODEL + quad * 8;

    float4 xr[8][2];
    f16x8 wr[4][3];
    #pragma unroll
    for (int d = 0; d < 8; d++) {
        xr[d][0] = *(const float4*)(xp + d * 32);
        xr[d][1] = *(const float4*)(xp + d * 32 + 4);
    }
    #pragma unroll
    for (int d = 0; d < 4; d++)
        #pragma unroll
        for (int nt = 0; nt < 3; nt++)
            wr[d][nt] = *(const f16x8*)(wp0 + (size_t)nt * 16 * D_MODEL + d * 32);

    f32x4 acc[3];
    #pragma unroll
    for (int nt = 0; nt < 3; nt++) acc[nt] = (f32x4){0.f, 0.f, 0.f, 0.f};

    #pragma unroll
    for (int w = 0; w < 32; w++) {
        const int k0 = w * 32;
        const int xs = w & 7;
        const int wsl = w & 3;
        float4 f0 = xr[xs][0];
        float4 f1 = xr[xs][1];
        f16x8 w0 = wr[wsl][0], w1 = wr[wsl][1], w2 = wr[wsl][2];
        if (k0 + 256 < D_MODEL) {
            xr[xs][0] = *(const float4*)(xp + k0 + 256);
            xr[xs][1] = *(const float4*)(xp + k0 + 256 + 4);
        }
        if (k0 + 128 < D_MODEL) {
            #pragma unroll
            for (int nt = 0; nt < 3; nt++)
                wr[wsl][nt] = *(const f16x8*)(wp0 + (size_t)nt * 16 * D_MODEL + k0 + 128);
        }
        f16x8 aX;
        aX[0] = (_Float16)f0.x; aX[1] = (_Float16)f0.y;
        aX[2] = (_Float16)f0.z; aX[3] = (_Float16)f0.w;
        aX[4] = (_Float16)f1.x; aX[5] = (_Float16)f1.y;
        aX[6] = (_Float16)f1.z; aX[7] = (_Float16)f1.w;
        acc[0] = __builtin_amdgcn_mfma_f32_16x16x32_f16(aX, w0, acc[0], 0, 0, 0);
        acc[1] = __builtin_amdgcn_mfma_f32_16x16x32_f16(aX, w1, acc[1], 0, 0, 0);
        acc[2] = __builtin_amdgcn_mfma_f32_16x16x32_f16(aX, w2, acc[2], 0, 0, 0);
    }

    // epilogue: C/D layout col=l16, row=quad*4+r
    const int batch = row0 / SEQ;
    const int seq0 = row0 - batch * SEQ + quad * 4;
    const int rbase = row0 + quad * 4;
    #pragma unroll
    for (int nt = 0; nt < 3; nt++) {
        int g = ncol0 + nt * 16 + l16;   // tensor choice is wave-uniform per nt
        if (g < 64) {
            float bias = bq[g];
            #pragma unroll
            for (int r = 0; r < 4; r++)
                q[(size_t)(rbase + r) * HEAD + g] = (_Float16)((acc[nt][r] + bias) * 0.125f);
        } else if (g < 128) {
            float bias = bk2[g - 64];
            #pragma unroll
            for (int r = 0; r < 4; r++)
                k[(size_t)(rbase + r) * HEAD + (g - 64)] = (_Float16)(acc[nt][r] + bias);
        } else {
            float bias = bv[g - 128];
            f16x4 pk;
            #pragma unroll
            for (int r = 0; r < 4; r++) pk[r] = (_Float16)(acc[nt][r] + bias);
            *(f16x4*)(vT + (size_t)(batch * HEAD + (g - 128)) * SEQ + seq0) = pk;
        }
    }
}

// ---------------- flash attention: 128-key LDS chunks, fp16 MFMA --------------
// grid (128,4) x 512 thr, 2 blocks/CU. Block: 16 queries x keys in 128-chunks
// (register-relay double buffer). Wave w: keys [16w,16w+16) of the chunk.
// S^T via x32 MFMA; exp(S^T) C-layout == B-layout of P^T -> O^T += V^T P^T
// via x16. No-max softmax => 8 wave partials additive; Oall aliases Ks/Vs LDS.
__global__ __launch_bounds__(512, 2) void attn_kernel(
    const _Float16* __restrict__ q, const _Float16* __restrict__ k,
    const _Float16* __restrict__ vT, float* __restrict__ out)
{
    const int tid = threadIdx.x;
    const int wave = tid >> 6;
    const int lane = tid & 63;
    const int l16 = lane & 15;
    const int quad = lane >> 4;
    const int b = blockIdx.y;
    const int q0 = blockIdx.x * 16;

    __shared__ __align__(16) char SM[128 * 72 * 2 + 64 * 136 * 2];  // 35840 B
    _Float16 (*Ks)[72] = (_Float16(*)[72])SM;                 // [key][d]
    _Float16 (*Vs)[136] = (_Float16(*)[136])(SM + 128 * 72 * 2);  // [d][key]
    float (*Oall)[16][68] = (float(*)[16][68])SM;             // aliases Ks/Vs (post-loop)
    __shared__ float Lall[8][16];

    // Q^T B-frags: n=query=l16, k=d=quad*8+j
    f16x8 bQ[2];
    {
        const _Float16* qp = q + (size_t)(b * SEQ + q0 + l16) * HEAD + quad * 8;
        bQ[0] = *(const f16x8*)qp;
        bQ[1] = *(const f16x8*)(qp + 32);
    }

    f32x4 O[4];
    #pragma unroll
    for (int dt = 0; dt < 4; dt++) O[dt] = (f32x4){0.f, 0.f, 0.f, 0.f};
    float lpart = 0.f;

    const _Float16* kb = k + (size_t)b * SEQ * HEAD;
    const _Float16* vb = vT + (size_t)b * HEAD * SEQ;

    // staging addresses (16B per thread per pass; 2 passes per tensor)
    const int krow = tid >> 3, kc8 = (tid & 7) * 8;
    const int vrow = tid >> 4, vc8 = (tid & 15) * 8;
    const _Float16* kg = kb + (size_t)krow * HEAD + kc8;
    const _Float16* vg = vb + (size_t)vrow * SEQ + vc8;

    f16x8 kr0 = *(const f16x8*)kg;
    f16x8 kr1 = *(const f16x8*)(kg + (size_t)64 * HEAD);
    f16x8 vr0 = *(const f16x8*)vg;
    f16x8 vr1 = *(const f16x8*)(vg + (size_t)32 * SEQ);

    for (int kc = 0; kc < SEQ; kc += 128) {
        *(f16x8*)&Ks[krow][kc8] = kr0;
        *(f16x8*)&Ks[krow + 64][kc8] = kr1;
        *(f16x8*)&Vs[vrow][vc8] = vr0;
        *(f16x8*)&Vs[vrow + 32][vc8] = vr1;
        if (kc + 128 < SEQ) {
            kr0 = *(const f16x8*)(kg + (size_t)(kc + 128) * HEAD);
            kr1 = *(const f16x8*)(kg + (size_t)(kc + 192) * HEAD);
            vr0 = *(const f16x8*)(vg + kc + 128);
            vr1 = *(const f16x8*)(vg + (size_t)32 * SEQ + kc + 128);
        }
        __syncthreads();

        // S^T strip: A = K[key=wave*16+l16][d], B = Q^T
        f16x8 aK0 = *(const f16x8*)&Ks[wave * 16 + l16][quad * 8];
        f16x8 aK1 = *(const f16x8*)&Ks[wave * 16 + l16][32 + quad * 8];
        f32x4 st = __builtin_amdgcn_mfma_f32_16x16x32_f16(aK0, bQ[0], (f32x4){0.f, 0.f, 0.f, 0.f}, 0, 0, 0);
        st = __builtin_amdgcn_mfma_f32_16x16x32_f16(aK1, bQ[1], st, 0, 0, 0);

        float p0 = __expf(st[0]);
        float p1 = __expf(st[1]);
        float p2 = __expf(st[2]);
        float p3 = __expf(st[3]);
        lpart += (p0 + p1) + (p2 + p3);
        f16x4 bP;
        bP[0] = (_Float16)p0; bP[1] = (_Float16)p1;
        bP[2] = (_Float16)p2; bP[3] = (_Float16)p3;

        // O^T += V^T P^T : A = Vs[d=dt*16+l16][key=wave*16+quad*4+i]
        #pragma unroll
        for (int dt = 0; dt < 4; dt++) {
            f16x4 aV = *(const f16x4*)&Vs[dt * 16 + l16][wave * 16 + quad * 4];
            O[dt] = __builtin_amdgcn_mfma_f32_16x16x16f16(aV, bP, O[dt], 0, 0, 0);
        }
        __syncthreads();
    }

    // l: lane holds partial for query l16; reduce across quads
    lpart += __shfl_xor(lpart, 16);
    lpart += __shfl_xor(lpart, 32);
    if (lane < 16) Lall[wave][l16] = lpart;
    // O^T C-layout: row = d-in-tile = quad*4+r, col = query = l16
    // (safe to alias Ks/Vs: loop ended with __syncthreads, no more Ks/Vs reads)
    #pragma unroll
    for (int dt = 0; dt < 4; dt++)
        #pragma unroll
        for (int r = 0; r < 4; r++)
            Oall[wave][l16][dt * 16 + quad * 4 + r] = O[dt][r];
    __syncthreads();

    // merge 8 additive wave partials: 512 thr x 2 outputs (16q x 64d)
    {
        int qi = tid >> 5;
        int dd = (tid & 31) * 2;
        float L = 0.f, o0 = 0.f, o1 = 0.f;
        #pragma unroll
        for (int w = 0; w < 8; w++) {
            L += Lall[w][qi];
            o0 += Oall[w][qi][dd];
            o1 += Oall[w][qi][dd + 1];
        }
        float inv = 1.f / L;
        float2 res = make_float2(o0 * inv, o1 * inv);
        *(float2*)(out + (size_t)(b * SEQ + q0 + qi) * HEAD + dd) = res;
    }
}

extern "C" void kernel_launch(void* const* d_in, const int* in_sizes, int n_in,
                              void* d_out, int out_size, void* d_ws, size_t ws_size,
                              hipStream_t stream) {
    const float* x  = (const float*)d_in[0];
    const float* wq = (const float*)d_in[1];
    const float* bq = (const float*)d_in[2];
    const float* wk = (const float*)d_in[3];
    const float* bk = (const float*)d_in[4];
    const float* wv = (const float*)d_in[5];
    const float* bv = (const float*)d_in[6];
    float* out = (float*)d_out;

    const size_t proj_elems = (size_t)BATCH * SEQ * HEAD;  // 524288
    _Float16* qh = (_Float16*)d_ws;
    _Float16* kh = qh + proj_elems;
    _Float16* vT = kh + proj_elems;
    _Float16* wT = vT + proj_elems;   // 192*1024 elems

    prep_w<<<dim3(16, 3), 256, 0, stream>>>(wq, wk, wv, wT);
    proj_kernel<<<dim3(BATCH * SEQ / 32), 512, 0, stream>>>(x, wT, bq, bk, bv, qh, kh, vT);
    attn_kernel<<<dim3(SEQ / 16, BATCH), 512, 0, stream>>>(qh, kh, vT, out);
}

// Round 6
// 125.460 us; speedup vs baseline: 1.0879x; 1.0879x over previous
//
#include <hip/hip_runtime.h>
#include <math.h>

#define D_MODEL 1024
#define HEAD 64
#define SEQ 2048
#define BATCH 4

typedef _Float16 f16x4 __attribute__((ext_vector_type(4)));
typedef _Float16 f16x8 __attribute__((ext_vector_type(8)));
typedef float f32x4 __attribute__((ext_vector_type(4)));

// ---------------- prepass: wT[192][1024] fp16 from wq/wk/wv fp32 [1024][64] ---
__global__ __launch_bounds__(256) void prep_w(
    const float* __restrict__ wq, const float* __restrict__ wk,
    const float* __restrict__ wv, _Float16* __restrict__ wT)
{
    const float* w = (blockIdx.y == 0) ? wq : (blockIdx.y == 1) ? wk : wv;
    const int kbase = blockIdx.x * 64;
    __shared__ float t[64][65];
    const int tid = threadIdx.x;
    #pragma unroll
    for (int i = 0; i < 16; i++) {
        int idx = tid + i * 256;
        int kk = idx >> 6, c = idx & 63;
        t[kk][c] = w[(size_t)(kbase + kk) * 64 + c];
    }
    __syncthreads();
    #pragma unroll
    for (int i = 0; i < 16; i++) {
        int idx = tid + i * 256;
        int c = idx >> 6, kk = idx & 63;
        wT[(size_t)(blockIdx.y * 64 + c) * 1024 + kbase + kk] = (_Float16)t[kk][c];
    }
}

// ---------------- fused QKV projection: LDS-relay staged, fp16 MFMA -----------
// grid 512 x 768 thr (12 waves), 2 blocks/CU -> 6 waves/SIMD. Block: 16 rows x
// all 192 fused cols; wave w owns cols [16w,16w+16). x staged fp32->fp16 into
// a double-buffered LDS relay (BK=128), read once from global total. wT f16x8
// streamed direct from global (L2-hot broadcast, 384KB). One barrier/chunk.
__global__ __launch_bounds__(768, 6) void proj_kernel(
    const float* __restrict__ x, const _Float16* __restrict__ wT,
    const float* __restrict__ bq, const float* __restrict__ bk2,
    const float* __restrict__ bv,
    _Float16* __restrict__ q, _Float16* __restrict__ k, _Float16* __restrict__ vT)
{
    const int tid = threadIdx.x;
    const int wave = tid >> 6;          // 0..11
    const int lane = tid & 63;
    const int l16 = lane & 15;
    const int quad = lane >> 4;
    const int row0 = blockIdx.x * 16;

    // pitch 136 f16 = 272B (16B-aligned); b128 reads sit at the bank floor
    __shared__ __align__(16) _Float16 Xs[2][16][136];

    // staging: threads 0..511 (waves 0..7) each load one float4 (16 rows x 128 k)
    const int srow = tid >> 5;          // 0..15 (tid<512)
    const int sc4 = tid & 31;           // float4 index within 128-k chunk
    const float4* xg = reinterpret_cast<const float4*>(x)
                     + (size_t)(row0 + srow) * (D_MODEL / 4) + sc4;

    float4 xr;
    if (tid < 512) xr = xg[0];

    const _Float16* wp = wT + (size_t)(wave * 16 + l16) * D_MODEL + quad * 8;

    f32x4 acc = (f32x4){0.f, 0.f, 0.f, 0.f};

    #pragma unroll
    for (int c = 0; c < 8; c++) {
        if (tid < 512) {
            f16x4 h;
            h[0] = (_Float16)xr.x; h[1] = (_Float16)xr.y;
            h[2] = (_Float16)xr.z; h[3] = (_Float16)xr.w;
            *(f16x4*)&Xs[c & 1][srow][sc4 * 4] = h;
            if (c < 7) xr = xg[(c + 1) * 32];
        }
        __syncthreads();
        #pragma unroll
        for (int kw = 0; kw < 4; kw++) {
            f16x8 aX = *(const f16x8*)&Xs[c & 1][l16][kw * 32 + quad * 8];
            f16x8 bW = *(const f16x8*)(wp + c * 128 + kw * 32);
            acc = __builtin_amdgcn_mfma_f32_16x16x32_f16(aX, bW, acc, 0, 0, 0);
        }
        // no second barrier: next iteration writes the OTHER buffer; the
        // barrier at the top of iteration c+1 orders reuse of this buffer.
    }

    // epilogue: C/D layout col=l16, row=quad*4+r; tensor choice wave-uniform
    const int g = wave * 16 + l16;       // fused col 0..191
    const int batch = row0 / SEQ;
    const int rbase = row0 + quad * 4;
    if (g < 64) {
        float bias = bq[g];
        #pragma unroll
        for (int r = 0; r < 4; r++)
            q[(size_t)(rbase + r) * HEAD + g] = (_Float16)((acc[r] + bias) * 0.125f);
    } else if (g < 128) {
        float bias = bk2[g - 64];
        #pragma unroll
        for (int r = 0; r < 4; r++)
            k[(size_t)(rbase + r) * HEAD + (g - 64)] = (_Float16)(acc[r] + bias);
    } else {
        float bias = bv[g - 128];
        f16x4 pk;
        #pragma unroll
        for (int r = 0; r < 4; r++) pk[r] = (_Float16)(acc[r] + bias);
        const int seq0 = row0 - batch * SEQ + quad * 4;
        *(f16x4*)(vT + (size_t)(batch * HEAD + (g - 128)) * SEQ + seq0) = pk;
    }
}

// ---------------- flash attention: 128-key LDS chunks, fp16 MFMA --------------
// grid (128,4) x 512 thr, 2 blocks/CU. Block: 16 queries x keys in 128-chunks
// (register-relay double buffer). Wave w: keys [16w,16w+16) of the chunk.
// S^T via x32 MFMA; exp(S^T) C-layout == B-layout of P^T -> O^T += V^T P^T
// via x16. No-max softmax => 8 wave partials additive; Oall aliases Ks/Vs LDS.
__global__ __launch_bounds__(512, 2) void attn_kernel(
    const _Float16* __restrict__ q, const _Float16* __restrict__ k,
    const _Float16* __restrict__ vT, float* __restrict__ out)
{
    const int tid = threadIdx.x;
    const int wave = tid >> 6;
    const int lane = tid & 63;
    const int l16 = lane & 15;
    const int quad = lane >> 4;
    const int b = blockIdx.y;
    const int q0 = blockIdx.x * 16;

    __shared__ __align__(16) char SM[128 * 72 * 2 + 64 * 136 * 2];  // 35840 B
    _Float16 (*Ks)[72] = (_Float16(*)[72])SM;                 // [key][d]
    _Float16 (*Vs)[136] = (_Float16(*)[136])(SM + 128 * 72 * 2);  // [d][key]
    float (*Oall)[16][68] = (float(*)[16][68])SM;             // aliases Ks/Vs (post-loop)
    __shared__ float Lall[8][16];

    // Q^T B-frags: n=query=l16, k=d=quad*8+j
    f16x8 bQ[2];
    {
        const _Float16* qp = q + (size_t)(b * SEQ + q0 + l16) * HEAD + quad * 8;
        bQ[0] = *(const f16x8*)qp;
        bQ[1] = *(const f16x8*)(qp + 32);
    }

    f32x4 O[4];
    #pragma unroll
    for (int dt = 0; dt < 4; dt++) O[dt] = (f32x4){0.f, 0.f, 0.f, 0.f};
    float lpart = 0.f;

    const _Float16* kb = k + (size_t)b * SEQ * HEAD;
    const _Float16* vb = vT + (size_t)b * HEAD * SEQ;

    // staging addresses (16B per thread per pass; 2 passes per tensor)
    const int krow = tid >> 3, kc8 = (tid & 7) * 8;
    const int vrow = tid >> 4, vc8 = (tid & 15) * 8;
    const _Float16* kg = kb + (size_t)krow * HEAD + kc8;
    const _Float16* vg = vb + (size_t)vrow * SEQ + vc8;

    f16x8 kr0 = *(const f16x8*)kg;
    f16x8 kr1 = *(const f16x8*)(kg + (size_t)64 * HEAD);
    f16x8 vr0 = *(const f16x8*)vg;
    f16x8 vr1 = *(const f16x8*)(vg + (size_t)32 * SEQ);

    for (int kc = 0; kc < SEQ; kc += 128) {
        *(f16x8*)&Ks[krow][kc8] = kr0;
        *(f16x8*)&Ks[krow + 64][kc8] = kr1;
        *(f16x8*)&Vs[vrow][vc8] = vr0;
        *(f16x8*)&Vs[vrow + 32][vc8] = vr1;
        if (kc + 128 < SEQ) {
            kr0 = *(const f16x8*)(kg + (size_t)(kc + 128) * HEAD);
            kr1 = *(const f16x8*)(kg + (size_t)(kc + 192) * HEAD);
            vr0 = *(const f16x8*)(vg + kc + 128);
            vr1 = *(const f16x8*)(vg + (size_t)32 * SEQ + kc + 128);
        }
        __syncthreads();

        // S^T strip: A = K[key=wave*16+l16][d], B = Q^T
        f16x8 aK0 = *(const f16x8*)&Ks[wave * 16 + l16][quad * 8];
        f16x8 aK1 = *(const f16x8*)&Ks[wave * 16 + l16][32 + quad * 8];
        f32x4 st = __builtin_amdgcn_mfma_f32_16x16x32_f16(aK0, bQ[0], (f32x4){0.f, 0.f, 0.f, 0.f}, 0, 0, 0);
        st = __builtin_amdgcn_mfma_f32_16x16x32_f16(aK1, bQ[1], st, 0, 0, 0);

        float p0 = __expf(st[0]);
        float p1 = __expf(st[1]);
        float p2 = __expf(st[2]);
        float p3 = __expf(st[3]);
        lpart += (p0 + p1) + (p2 + p3);
        f16x4 bP;
        bP[0] = (_Float16)p0; bP[1] = (_Float16)p1;
        bP[2] = (_Float16)p2; bP[3] = (_Float16)p3;

        // O^T += V^T P^T : A = Vs[d=dt*16+l16][key=wave*16+quad*4+i]
        #pragma unroll
        for (int dt = 0; dt < 4; dt++) {
            f16x4 aV = *(const f16x4*)&Vs[dt * 16 + l16][wave * 16 + quad * 4];
            O[dt] = __builtin_amdgcn_mfma_f32_16x16x16f16(aV, bP, O[dt], 0, 0, 0);
        }
        __syncthreads();
    }

    // l: lane holds partial for query l16; reduce across quads
    lpart += __shfl_xor(lpart, 16);
    lpart += __shfl_xor(lpart, 32);
    if (lane < 16) Lall[wave][l16] = lpart;
    // O^T C-layout: row = d-in-tile = quad*4+r, col = query = l16
    // (safe to alias Ks/Vs: loop ended with __syncthreads, no more Ks/Vs reads)
    #pragma unroll
    for (int dt = 0; dt < 4; dt++)
        #pragma unroll
        for (int r = 0; r < 4; r++)
            Oall[wave][l16][dt * 16 + quad * 4 + r] = O[dt][r];
    __syncthreads();

    // merge 8 additive wave partials: 512 thr x 2 outputs (16q x 64d)
    {
        int qi = tid >> 5;
        int dd = (tid & 31) * 2;
        float L = 0.f, o0 = 0.f, o1 = 0.f;
        #pragma unroll
        for (int w = 0; w < 8; w++) {
            L += Lall[w][qi];
            o0 += Oall[w][qi][dd];
            o1 += Oall[w][qi][dd + 1];
        }
        float inv = 1.f / L;
        float2 res = make_float2(o0 * inv, o1 * inv);
        *(float2*)(out + (size_t)(b * SEQ + q0 + qi) * HEAD + dd) = res;
    }
}

extern "C" void kernel_launch(void* const* d_in, const int* in_sizes, int n_in,
                              void* d_out, int out_size, void* d_ws, size_t ws_size,
                              hipStream_t stream) {
    const float* x  = (const float*)d_in[0];
    const float* wq = (const float*)d_in[1];
    const float* bq = (const float*)d_in[2];
    const float* wk = (const float*)d_in[3];
    const float* bk = (const float*)d_in[4];
    const float* wv = (const float*)d_in[5];
    const float* bv = (const float*)d_in[6];
    float* out = (float*)d_out;

    const size_t proj_elems = (size_t)BATCH * SEQ * HEAD;  // 524288
    _Float16* qh = (_Float16*)d_ws;
    _Float16* kh = qh + proj_elems;
    _Float16* vT = kh + proj_elems;
    _Float16* wT = vT + proj_elems;   // 192*1024 elems

    prep_w<<<dim3(16, 3), 256, 0, stream>>>(wq, wk, wv, wT);
    proj_kernel<<<dim3(BATCH * SEQ / 16), 768, 0, stream>>>(x, wT, bq, bk, bv, qh, kh, vT);
    attn_kernel<<<dim3(SEQ / 16, BATCH), 512, 0, stream>>>(qh, kh, vT, out);
}

// Round 7
// 123.952 us; speedup vs baseline: 1.1011x; 1.0122x over previous
//
#include <hip/hip_runtime.h>
#include <math.h>

#define D_MODEL 1024
#define HEAD 64
#define SEQ 2048
#define BATCH 4

typedef _Float16 f16x4 __attribute__((ext_vector_type(4)));
typedef _Float16 f16x8 __attribute__((ext_vector_type(8)));
typedef float f32x4 __attribute__((ext_vector_type(4)));

// ---------------- prepass: wT[192][1024] fp16 from wq/wk/wv fp32 [1024][64] ---
__global__ __launch_bounds__(256) void prep_w(
    const float* __restrict__ wq, const float* __restrict__ wk,
    const float* __restrict__ wv, _Float16* __restrict__ wT)
{
    const float* w = (blockIdx.y == 0) ? wq : (blockIdx.y == 1) ? wk : wv;
    const int kbase = blockIdx.x * 64;
    __shared__ float t[64][65];
    const int tid = threadIdx.x;
    #pragma unroll
    for (int i = 0; i < 16; i++) {
        int idx = tid + i * 256;
        int kk = idx >> 6, c = idx & 63;
        t[kk][c] = w[(size_t)(kbase + kk) * 64 + c];
    }
    __syncthreads();
    #pragma unroll
    for (int i = 0; i < 16; i++) {
        int idx = tid + i * 256;
        int c = idx >> 6, kk = idx & 63;
        wT[(size_t)(blockIdx.y * 64 + c) * 1024 + kbase + kk] = (_Float16)t[kk][c];
    }
}

// ---------------- fused QKV projection: pipelined LDS relay, fp16 MFMA --------
// grid 512 x 768 thr (12 waves, 2 blocks/CU). Block: 16 rows x 192 fused cols;
// wave w owns cols [16w,16w+16). Chunk loop order: barrier -> issue wT loads
// (L2, oldest) -> issue x prefetch (HBM, youngest in vmcnt FIFO) -> MFMA from
// LDS buf[c&1] -> ds_write prefetch into buf[(c+1)&1]. Prefetch crosses the
// compute phase, not the barrier (barrier drains vmcnt on gfx950).
__global__ __launch_bounds__(768, 6) void proj_kernel(
    const float* __restrict__ x, const _Float16* __restrict__ wT,
    const float* __restrict__ bq, const float* __restrict__ bk2,
    const float* __restrict__ bv,
    _Float16* __restrict__ q, _Float16* __restrict__ k, _Float16* __restrict__ vT)
{
    const int tid = threadIdx.x;
    const int wave = tid >> 6;          // 0..11
    const int lane = tid & 63;
    const int l16 = lane & 15;
    const int quad = lane >> 4;
    const int row0 = blockIdx.x * 16;

    __shared__ __align__(16) _Float16 Xs[2][16][136];   // pitch 272B

    // staging: threads 0..511 each own one float4 of the 16x128 fp32 chunk
    const int srow = tid >> 5;          // 0..15 (tid<512)
    const int sc4 = tid & 31;
    const float4* xg = reinterpret_cast<const float4*>(x)
                     + (size_t)(row0 + srow) * (D_MODEL / 4) + sc4;

    const _Float16* wp = wT + (size_t)(wave * 16 + l16) * D_MODEL + quad * 8;

    // prologue: chunk 0 into buf 0
    float4 xr;
    if (tid < 512) {
        xr = xg[0];
        f16x4 h;
        h[0] = (_Float16)xr.x; h[1] = (_Float16)xr.y;
        h[2] = (_Float16)xr.z; h[3] = (_Float16)xr.w;
        *(f16x4*)&Xs[0][srow][sc4 * 4] = h;
    }

    f32x4 acc = (f32x4){0.f, 0.f, 0.f, 0.f};

    #pragma unroll 1
    for (int c = 0; c < 8; c++) {
        __syncthreads();                 // publish buf[c&1]; guard buf[(c+1)&1] reuse
        // wT loads for THIS chunk first (oldest in FIFO; L2-fast)
        f16x8 bw0 = *(const f16x8*)(wp + c * 128);
        f16x8 bw1 = *(const f16x8*)(wp + c * 128 + 32);
        f16x8 bw2 = *(const f16x8*)(wp + c * 128 + 64);
        f16x8 bw3 = *(const f16x8*)(wp + c * 128 + 96);
        // x prefetch for NEXT chunk (youngest; stays in flight through compute)
        if (c < 7 && tid < 512) xr = xg[(c + 1) * 32];
        const int bsel = c & 1;
        f16x8 aX0 = *(const f16x8*)&Xs[bsel][l16][0 * 32 + quad * 8];
        f16x8 aX1 = *(const f16x8*)&Xs[bsel][l16][1 * 32 + quad * 8];
        f16x8 aX2 = *(const f16x8*)&Xs[bsel][l16][2 * 32 + quad * 8];
        f16x8 aX3 = *(const f16x8*)&Xs[bsel][l16][3 * 32 + quad * 8];
        acc = __builtin_amdgcn_mfma_f32_16x16x32_f16(aX0, bw0, acc, 0, 0, 0);
        acc = __builtin_amdgcn_mfma_f32_16x16x32_f16(aX1, bw1, acc, 0, 0, 0);
        acc = __builtin_amdgcn_mfma_f32_16x16x32_f16(aX2, bw2, acc, 0, 0, 0);
        acc = __builtin_amdgcn_mfma_f32_16x16x32_f16(aX3, bw3, acc, 0, 0, 0);
        if (c < 7 && tid < 512) {
            f16x4 h;                     // vmcnt wait for xr lands HERE, post-compute
            h[0] = (_Float16)xr.x; h[1] = (_Float16)xr.y;
            h[2] = (_Float16)xr.z; h[3] = (_Float16)xr.w;
            *(f16x4*)&Xs[bsel ^ 1][srow][sc4 * 4] = h;
        }
    }

    // epilogue: C/D layout col=l16, row=quad*4+r; tensor choice wave-uniform
    const int g = wave * 16 + l16;       // fused col 0..191
    const int batch = row0 / SEQ;
    const int rbase = row0 + quad * 4;
    if (g < 64) {
        float bias = bq[g];
        #pragma unroll
        for (int r = 0; r < 4; r++)
            q[(size_t)(rbase + r) * HEAD + g] = (_Float16)((acc[r] + bias) * 0.125f);
    } else if (g < 128) {
        float bias = bk2[g - 64];
        #pragma unroll
        for (int r = 0; r < 4; r++)
            k[(size_t)(rbase + r) * HEAD + (g - 64)] = (_Float16)(acc[r] + bias);
    } else {
        float bias = bv[g - 128];
        f16x4 pk;
        #pragma unroll
        for (int r = 0; r < 4; r++) pk[r] = (_Float16)(acc[r] + bias);
        const int seq0 = row0 - batch * SEQ + quad * 4;
        *(f16x4*)(vT + (size_t)(batch * HEAD + (g - 128)) * SEQ + seq0) = pk;
    }
}

// ---------------- flash attention: pipelined 128-key chunks, fp16 MFMA --------
// grid (128,4) x 512 thr, 2 blocks/CU (LDS 71.7KB). Chunk loop: barrier ->
// issue next-chunk K/V loads -> compute (LDS-only: S^T x32 MFMA, exp, PV x16
// via the C==B layout identity) -> ds_write into buf^1. No-max softmax =>
// 8 wave partials additive. Oall aliases Ks (guarded by post-loop barrier).
__global__ __launch_bounds__(512, 4) void attn_kernel(
    const _Float16* __restrict__ q, const _Float16* __restrict__ k,
    const _Float16* __restrict__ vT, float* __restrict__ out)
{
    const int tid = threadIdx.x;
    const int wave = tid >> 6;
    const int lane = tid & 63;
    const int l16 = lane & 15;
    const int quad = lane >> 4;
    const int b = blockIdx.y;
    const int q0 = blockIdx.x * 16;

    __shared__ __align__(16) char SM[2 * 18432 + 2 * 17408];   // 71680 B
    _Float16 (*Ks)[128][72] = (_Float16(*)[128][72])SM;
    _Float16 (*Vs)[64][136] = (_Float16(*)[64][136])(SM + 2 * 18432);
    float (*Oall)[16][68] = (float(*)[16][68])SM;   // alias; used post-loop only
    __shared__ float Lall[8][16];

    // Q^T B-frags: n=query=l16, k=d=quad*8+j
    f16x8 bQ[2];
    {
        const _Float16* qp = q + (size_t)(b * SEQ + q0 + l16) * HEAD + quad * 8;
        bQ[0] = *(const f16x8*)qp;
        bQ[1] = *(const f16x8*)(qp + 32);
    }

    f32x4 O[4];
    #pragma unroll
    for (int dt = 0; dt < 4; dt++) O[dt] = (f32x4){0.f, 0.f, 0.f, 0.f};
    float lpart = 0.f;

    const _Float16* kb = k + (size_t)b * SEQ * HEAD;
    const _Float16* vb = vT + (size_t)b * HEAD * SEQ;

    const int krow = tid >> 3, kc8 = (tid & 7) * 8;
    const int vrow = tid >> 4, vc8 = (tid & 15) * 8;
    const _Float16* kg = kb + (size_t)krow * HEAD + kc8;
    const _Float16* vg = vb + (size_t)vrow * SEQ + vc8;

    // prologue: chunk 0 into buf 0
    f16x8 kr0 = *(const f16x8*)kg;
    f16x8 kr1 = *(const f16x8*)(kg + (size_t)64 * HEAD);
    f16x8 vr0 = *(const f16x8*)vg;
    f16x8 vr1 = *(const f16x8*)(vg + (size_t)32 * SEQ);
    *(f16x8*)&Ks[0][krow][kc8] = kr0;
    *(f16x8*)&Ks[0][krow + 64][kc8] = kr1;
    *(f16x8*)&Vs[0][vrow][vc8] = vr0;
    *(f16x8*)&Vs[0][vrow + 32][vc8] = vr1;

    #pragma unroll 1
    for (int c = 0; c < 16; c++) {
        __syncthreads();                 // publish buf[c&1]; guard buf^1 reuse
        if (c < 15) {                    // prefetch issued AFTER barrier
            const int kc2 = (c + 1) * 128;
            kr0 = *(const f16x8*)(kg + (size_t)kc2 * HEAD);
            kr1 = *(const f16x8*)(kg + (size_t)(kc2 + 64) * HEAD);
            vr0 = *(const f16x8*)(vg + kc2);
            vr1 = *(const f16x8*)(vg + (size_t)32 * SEQ + kc2);
        }
        const int bsel = c & 1;
        // S^T strip: A = K[key=wave*16+l16][d], B = Q^T  (LDS-only compute)
        f16x8 aK0 = *(const f16x8*)&Ks[bsel][wave * 16 + l16][quad * 8];
        f16x8 aK1 = *(const f16x8*)&Ks[bsel][wave * 16 + l16][32 + quad * 8];
        f32x4 st = __builtin_amdgcn_mfma_f32_16x16x32_f16(aK0, bQ[0], (f32x4){0.f, 0.f, 0.f, 0.f}, 0, 0, 0);
        st = __builtin_amdgcn_mfma_f32_16x16x32_f16(aK1, bQ[1], st, 0, 0, 0);

        float p0 = __expf(st[0]);
        float p1 = __expf(st[1]);
        float p2 = __expf(st[2]);
        float p3 = __expf(st[3]);
        lpart += (p0 + p1) + (p2 + p3);
        f16x4 bP;
        bP[0] = (_Float16)p0; bP[1] = (_Float16)p1;
        bP[2] = (_Float16)p2; bP[3] = (_Float16)p3;

        // O^T += V^T P^T : A = Vs[d=dt*16+l16][key=wave*16+quad*4+i]
        #pragma unroll
        for (int dt = 0; dt < 4; dt++) {
            f16x4 aV = *(const f16x4*)&Vs[bsel][dt * 16 + l16][wave * 16 + quad * 4];
            O[dt] = __builtin_amdgcn_mfma_f32_16x16x16f16(aV, bP, O[dt], 0, 0, 0);
        }
        if (c < 15) {                    // vmcnt wait for prefetch lands here
            *(f16x8*)&Ks[bsel ^ 1][krow][kc8] = kr0;
            *(f16x8*)&Ks[bsel ^ 1][krow + 64][kc8] = kr1;
            *(f16x8*)&Vs[bsel ^ 1][vrow][vc8] = vr0;
            *(f16x8*)&Vs[bsel ^ 1][vrow + 32][vc8] = vr1;
        }
    }
    __syncthreads();   // all waves done reading Ks/Vs before Oall alias writes

    // l: lane holds partial for query l16; reduce across quads
    lpart += __shfl_xor(lpart, 16);
    lpart += __shfl_xor(lpart, 32);
    if (lane < 16) Lall[wave][l16] = lpart;
    // O^T C-layout: row = d-in-tile = quad*4+r, col = query = l16
    #pragma unroll
    for (int dt = 0; dt < 4; dt++)
        #pragma unroll
        for (int r = 0; r < 4; r++)
            Oall[wave][l16][dt * 16 + quad * 4 + r] = O[dt][r];
    __syncthreads();

    // merge 8 additive wave partials: 512 thr x 2 outputs (16q x 64d)
    {
        int qi = tid >> 5;
        int dd = (tid & 31) * 2;
        float L = 0.f, o0 = 0.f, o1 = 0.f;
        #pragma unroll
        for (int w = 0; w < 8; w++) {
            L += Lall[w][qi];
            o0 += Oall[w][qi][dd];
            o1 += Oall[w][qi][dd + 1];
        }
        float inv = 1.f / L;
        float2 res = make_float2(o0 * inv, o1 * inv);
        *(float2*)(out + (size_t)(b * SEQ + q0 + qi) * HEAD + dd) = res;
    }
}

extern "C" void kernel_launch(void* const* d_in, const int* in_sizes, int n_in,
                              void* d_out, int out_size, void* d_ws, size_t ws_size,
                              hipStream_t stream) {
    const float* x  = (const float*)d_in[0];
    const float* wq = (const float*)d_in[1];
    const float* bq = (const float*)d_in[2];
    const float* wk = (const float*)d_in[3];
    const float* bk = (const float*)d_in[4];
    const float* wv = (const float*)d_in[5];
    const float* bv = (const float*)d_in[6];
    float* out = (float*)d_out;

    const size_t proj_elems = (size_t)BATCH * SEQ * HEAD;  // 524288
    _Float16* qh = (_Float16*)d_ws;
    _Float16* kh = qh + proj_elems;
    _Float16* vT = kh + proj_elems;
    _Float16* wT = vT + proj_elems;   // 192*1024 elems

    prep_w<<<dim3(16, 3), 256, 0, stream>>>(wq, wk, wv, wT);
    proj_kernel<<<dim3(BATCH * SEQ / 16), 768, 0, stream>>>(x, wT, bq, bk, bv, qh, kh, vT);
    attn_kernel<<<dim3(SEQ / 16, BATCH), 512, 0, stream>>>(qh, kh, vT, out);
}